// Round 12
// baseline (231.239 us; speedup 1.0000x reference)
//
#include <hip/hip_runtime.h>
#include <cstdint>
#include <cstddef>

#define B_ 16
#define S_ 2048
#define D_ 128
#define NW 8             // waves per block
#define MROWS 16         // q-rows per block (all waves share)
#define KPW 256          // keys per wave
#define OST 136          // opart row stride in halves

typedef float  f32x4 __attribute__((ext_vector_type(4)));
typedef _Float16 f16x8 __attribute__((ext_vector_type(8)));
typedef _Float16 f16x4 __attribute__((ext_vector_type(4)));

// log2(e) / sqrt(128)
#define SCALE_ 0.12751743f

#define NE_ ((size_t)B_ * S_ * D_)   // 4,194,304 per tensor
#define VT2_BATCH 262144             // halves per batch in Vt2 (512KB f16)

// ---------------- pre-pass (verified R5-R11) ----------------
// blocks [0,2048): V -> Vt2, PV-fragment-native tiled layout:
//   Vt2[((b*128 + kt)*8 + dt)*64 + lane][i]  (f16, i=0..3)
//   holds V[b][key = kt*16 + 4*(lane>>4) + i][d = dt*16 + (lane&15)]
// blocks [2048,3072): K f32 -> f16 row-major
__global__ void prepass_kernel(const float* __restrict__ K,
                               const float* __restrict__ V,
                               _Float16* __restrict__ Kh,
                               _Float16* __restrict__ Vt2) {
  const int blk = blockIdx.x;
  if (blk < 2048) {
    const int b  = blk >> 7;
    const int kt = blk & 127;
    const int tid = threadIdx.x;
    const int lg = tid >> 6;
    const int i  = (tid >> 4) & 3;
    const int lr = tid & 15;
    const size_t vrow = ((size_t)b * S_ + kt * 16 + 4 * lg + i) * D_;
    const size_t obase = (((size_t)(b * 128 + kt) * 8) * 64 + lg * 16 + lr) * 4 + i;
#pragma unroll
    for (int dt = 0; dt < 8; ++dt) {
      float val = V[vrow + dt * 16 + lr];
      Vt2[obase + (size_t)dt * 256] = (_Float16)val;
    }
  } else {
    int rel = blk - 2048;
    const int n4 = (int)(NE_ / 4);
    for (int i = rel * 256 + (int)threadIdx.x; i < n4; i += 1024 * 256) {
      f32x4 v = ((const f32x4*)K)[i];
      f16x4 h;
      for (int j = 0; j < 4; ++j) h[j] = (_Float16)v[j];
      ((f16x4*)Kh)[i] = h;
    }
  }
}

// ---------------- fused attention, single kernel ----------------
// 2048 blocks x 8 waves. Block owns 16 q-rows; wave w covers keys
// [256w, 256w+256). Swapped QK^T (verified R5-R11): lane(lr,lg) reg r
// holds S^T[key=16t+4lg+r][qrow=lr]; exp+f16-pack -> pp[t] IS the
// A-frag of mfma_f32_16x16x16_f16. One barrier for the row-sum
// exchange; PV runs with normalized NT attn stores interleaved
// (NT keeps Kh/Vt2 L2-resident: R8 cacheable FETCH=41MB vs R10 NT
// 16MB); O partials reduced 8-way via LDS at the end.
// Registers: pp 32 + o 32 + bq 16 + temps ~ 110 -> bounds(512,4)
// gives 4 waves/SIMD, 2 blocks/CU (LDS 35KB). All reg arrays fully
// unrolled (scratch lesson, R5/R6).
template <bool WS>
__global__ __launch_bounds__(512, 4)
void attn_fused(const float* __restrict__ Qf, const float* __restrict__ Kf,
                const float* __restrict__ Vf,
                const _Float16* __restrict__ Kh, const _Float16* __restrict__ Vt2,
                float* __restrict__ outO, float* __restrict__ outA) {
  __shared__ _Float16 opart[NW][MROWS][OST];   // 34.8 KB
  __shared__ float wsum[NW][MROWS];

  const int tid = threadIdx.x;
  const int w = tid >> 6, lane = tid & 63, lg = lane >> 4, lr = lane & 15;
  const int blk = blockIdx.x;
  const int gwid = (blk & 7) * 256 + (blk >> 3);   // XCD-local batches
  const int b  = gwid >> 7;          // 0..15
  const int q0 = (gwid & 127) * MROWS;
  const int key0 = w * KPW;

  // ---- Q B-frags: B[k=32kk+8lg+j][n=qrow=lr] ----
  f16x8 bq[4];
  {
    const float* qp = Qf + ((size_t)b * S_ + q0 + lr) * D_;
#pragma unroll
    for (int kk = 0; kk < 4; ++kk) {
      const float* p = qp + kk * 32 + lg * 8;
      f32x4 v0 = *(const f32x4*)p, v1 = *(const f32x4*)(p + 4);
      f16x8 a;
#pragma unroll
      for (int j = 0; j < 4; ++j) { a[j] = (_Float16)v0[j]; a[4 + j] = (_Float16)v1[j]; }
      bq[kk] = a;
    }
  }

  // ---- Phase 1: S^T = K·Q^T, P = exp packed into pp regs ----
  f16x4 pp[16];             // 32 VGPRs
  float psum = 0.f;
#pragma unroll
  for (int t = 0; t < 16; ++t) {
    f32x4 acc = {0.f, 0.f, 0.f, 0.f};
    const size_t krow = (size_t)b * S_ + key0 + 16 * t + lr;
#pragma unroll
    for (int kk = 0; kk < 4; ++kk) {
      f16x8 ka;
      if constexpr (WS) {
        ka = *(const f16x8*)(Kh + krow * D_ + kk * 32 + lg * 8);
      } else {
        const float* p = Kf + krow * D_ + kk * 32 + lg * 8;
        f32x4 v0 = *(const f32x4*)p, v1 = *(const f32x4*)(p + 4);
#pragma unroll
        for (int j = 0; j < 4; ++j) { ka[j] = (_Float16)v0[j]; ka[4 + j] = (_Float16)v1[j]; }
      }
      acc = __builtin_amdgcn_mfma_f32_16x16x32_f16(ka, bq[kk], acc, 0, 0, 0);
    }
    f16x4 p;
#pragma unroll
    for (int r = 0; r < 4; ++r) {
      float e = __builtin_amdgcn_exp2f(acc[r] * SCALE_);
      psum += e;
      p[r] = (_Float16)e;
    }
    pp[t] = p;
  }

  // ---- row partial sums -> wsum ----
  psum += __shfl_xor(psum, 16);
  psum += __shfl_xor(psum, 32);
  if (lg == 0) wsum[w][lr] = psum;

  __syncthreads();   // barrier #1: wsum ready

  float srow = 0.f;
#pragma unroll
  for (int wv = 0; wv < NW; ++wv) srow += wsum[wv][lr];
  const float inv = 1.0f / srow;   // denominator for q-row lr

  // ---- Phase 2: PV (16x16x16, pp IS the A-frag) with interleaved
  //      normalized NT attn stores (2 per dt iteration) ----
  const _Float16* vbase = nullptr;
  if constexpr (WS)
    vbase = Vt2 + (size_t)b * VT2_BATCH + (size_t)(key0 >> 4) * 2048 + lane * 4;
  float* arow = outA + ((size_t)b * S_ + q0 + lr) * S_ + key0 + lg * 4;

  f32x4 o0 = {0.f,0.f,0.f,0.f}, o1 = {0.f,0.f,0.f,0.f}, o2 = {0.f,0.f,0.f,0.f},
        o3 = {0.f,0.f,0.f,0.f}, o4 = {0.f,0.f,0.f,0.f}, o5 = {0.f,0.f,0.f,0.f},
        o6 = {0.f,0.f,0.f,0.f}, o7 = {0.f,0.f,0.f,0.f};

#define PV_DT(dt, odt)                                                        \
  {                                                                           \
    _Pragma("unroll")                                                         \
    for (int t = 0; t < 16; ++t) {                                            \
      f16x4 bv;                                                               \
      if constexpr (WS) {                                                     \
        bv = *(const f16x4*)(vbase + (size_t)t * 2048 + dt * 256);            \
      } else {                                                                \
        _Pragma("unroll")                                                     \
        for (int i = 0; i < 4; ++i)                                           \
          bv[i] = (_Float16)Vf[((size_t)b * S_ + key0 + 16 * t + 4 * lg + i)  \
                               * D_ + dt * 16 + lr];                          \
      }                                                                       \
      odt = __builtin_amdgcn_mfma_f32_16x16x16f16(pp[t], bv, odt, 0, 0, 0);   \
    }                                                                         \
    _Pragma("unroll")                                                         \
    for (int tt = 0; tt < 2; ++tt) {                                          \
      const int ts = dt * 2 + tt;                                             \
      f32x4 av;                                                               \
      _Pragma("unroll")                                                       \
      for (int j = 0; j < 4; ++j) av[j] = (float)pp[ts][j] * inv;             \
      __builtin_nontemporal_store(av, (f32x4*)(arow + 16 * ts));              \
    }                                                                         \
  }

  PV_DT(0, o0) PV_DT(1, o1) PV_DT(2, o2) PV_DT(3, o3)
  PV_DT(4, o4) PV_DT(5, o5) PV_DT(6, o6) PV_DT(7, o7)
#undef PV_DT

  // ---- O partials -> LDS. Lane holds O[qrow=4lg+r][d=16dt+lr] ----
#pragma unroll
  for (int r = 0; r < 4; ++r) {
    opart[w][4 * lg + r][0 * 16 + lr] = (_Float16)o0[r];
    opart[w][4 * lg + r][1 * 16 + lr] = (_Float16)o1[r];
    opart[w][4 * lg + r][2 * 16 + lr] = (_Float16)o2[r];
    opart[w][4 * lg + r][3 * 16 + lr] = (_Float16)o3[r];
    opart[w][4 * lg + r][4 * 16 + lr] = (_Float16)o4[r];
    opart[w][4 * lg + r][5 * 16 + lr] = (_Float16)o5[r];
    opart[w][4 * lg + r][6 * 16 + lr] = (_Float16)o6[r];
    opart[w][4 * lg + r][7 * 16 + lr] = (_Float16)o7[r];
  }

  __syncthreads();   // barrier #2: opart ready

  // ---- O: fixed-order 8-way reduction, 16B/thread store ----
  {
    const int row = tid >> 5;          // 0..15
    const int dc  = (tid & 31) * 4;    // 0..124
    float racc[4] = {0.f, 0.f, 0.f, 0.f};
#pragma unroll
    for (int wv = 0; wv < NW; ++wv) {
      f16x4 x = *(const f16x4*)&opart[wv][row][dc];
#pragma unroll
      for (int j = 0; j < 4; ++j) racc[j] += (float)x[j];
    }
    float so = 0.f;
#pragma unroll
    for (int wv = 0; wv < NW; ++wv) so += wsum[wv][row];
    const float invr = 1.0f / so;
    f32x4 rv;
#pragma unroll
    for (int j = 0; j < 4; ++j) rv[j] = racc[j] * invr;
    *(f32x4*)(outO + ((size_t)b * S_ + q0 + row) * D_ + dc) = rv;
  }
}

extern "C" void kernel_launch(void* const* d_in, const int* in_sizes, int n_in,
                              void* d_out, int out_size, void* d_ws, size_t ws_size,
                              hipStream_t stream) {
  const float* Q = (const float*)d_in[0];
  const float* K = (const float*)d_in[1];
  const float* V = (const float*)d_in[2];
  float* outO = (float*)d_out;
  float* outA = outO + NE_;

  const size_t need = 2 * NE_ * sizeof(_Float16);   // 16 MiB (Kh + Vt2)
  const int nblk = B_ * S_ / MROWS;                  // 2048

  if (ws_size >= need) {
    _Float16* Kh  = (_Float16*)d_ws;
    _Float16* Vt2 = Kh + NE_;
    prepass_kernel<<<3072, 256, 0, stream>>>(K, V, Kh, Vt2);
    attn_fused<true><<<nblk, 512, 0, stream>>>(Q, nullptr, nullptr,
                                               Kh, Vt2, outO, outA);
  } else {
    attn_fused<false><<<nblk, 512, 0, stream>>>(Q, K, V,
                                                nullptr, nullptr, outO, outA);
  }
}